// Round 2
// baseline (287.994 us; speedup 1.0000x reference)
//
#include <hip/hip_runtime.h>
#include <stdint.h>

// RelationalNetwork: B=8, C=64, O=256, TE=128, GT=FP=256, A=32
// R2: 64-row tiles (32KiB LDS -> 4 wg/CU, 16 waves/CU), conflict-free XOR
// swizzle f(row)=((row&7)<<2)|((row>>3)&3), fp32 U/V, atomicAdd epilogue
// (no part buffer), i/j computed in-kernel, merged prep kernel.

#define NPAIR 32896   // 256*257/2
#define NTILE 514     // 64 pairs per tile

using short8  = __attribute__((ext_vector_type(8))) short;
using float4v = __attribute__((ext_vector_type(4))) float;

__device__ __forceinline__ unsigned short f2bf(float f) {
    union { float f; unsigned u; } c; c.f = f;
    unsigned u = c.u;
    u += 0x7FFFu + ((u >> 16) & 1u);   // RNE
    return (unsigned short)(u >> 16);
}
__device__ __forceinline__ unsigned pk2(float lo, float hi) {
    return (unsigned)f2bf(lo) | ((unsigned)f2bf(hi) << 16);
}

// ---- prep: qb[b,d] = code.W1[132:260]+b1 (blocks 0..7); W2/W3 transpose+bf16
__global__ void k_prep(const float* __restrict__ code, const float* __restrict__ w1,
                       const float* __restrict__ b1,
                       const float* __restrict__ w2, const float* __restrict__ w3,
                       float* __restrict__ qb,
                       unsigned short* __restrict__ w2t, unsigned short* __restrict__ w3t) {
    const int bx = blockIdx.x;
    if (bx < 8) {
        const int b = bx, d = threadIdx.x;
        float s = b1[d];
        const float* w = w1 + 132 * 256 + d;
        const float* c = code + b * 128;
        #pragma unroll 4
        for (int t = 0; t < 128; ++t) s += c[t] * w[t * 256];
        qb[b * 256 + d] = s;
    } else {
        __shared__ float t[64][65];
        const int id = bx - 8;
        const float* src = (id >= 16) ? w3 : w2;
        unsigned short* dst = (id >= 16) ? w3t : w2t;
        const int rem = id & 15;
        const int k0 = (rem >> 2) * 64, n0 = (rem & 3) * 64;
        const int tx = threadIdx.x & 63, ty = threadIdx.x >> 6;
        #pragma unroll
        for (int r = ty; r < 64; r += 4)
            t[r][tx] = src[(k0 + r) * 256 + n0 + tx];
        __syncthreads();
        #pragma unroll
        for (int r = ty; r < 64; r += 4)
            dst[(n0 + r) * 256 + k0 + tx] = f2bf(t[tx][r]);
    }
}

// ---- U,V precompute (fp32), code-term + bias folded into U ---------------
__global__ void k_uv(const float* __restrict__ x, const float* __restrict__ w1,
                     const float* __restrict__ qb,
                     float* __restrict__ uf, float* __restrict__ vf) {
    const int i = blockIdx.x, b = blockIdx.y, d = threadIdx.x;
    float su = qb[b * 256 + d];
    float sv = 0.f;
    const float* xp = x + (b * 64) * 256 + i;
    #pragma unroll 4
    for (int c = 0; c < 64; ++c) {
        float xv = xp[c * 256];
        su += xv * w1[c * 256 + d];
        sv += xv * w1[(66 + c) * 256 + d];
    }
    float yy = (float)(i >> 4) * (2.0f / 15.0f) - 1.0f;
    float xx = (float)(i & 15) * (2.0f / 15.0f) - 1.0f;
    su += yy * w1[64 * 256 + d] + xx * w1[65 * 256 + d];
    sv += yy * w1[130 * 256 + d] + xx * w1[131 * 256 + d];
    uf[(b * 256 + i) * 256 + d] = su;
    vf[(b * 256 + i) * 256 + d] = sv;
}

// ---- fused g_theta L2+L3 + tril row-sum (64-row tiles) -------------------
// LDS 64x256 bf16 = 32 KiB. Swizzle: logical 8-elem chunk c of row r lives at
// byte offset r*512 + ((c ^ f(r))<<4), f(r)=((r&7)<<2)|((r>>3)&3).
// All three LDS phases are exactly 2 lanes/bank (free).
__global__ __launch_bounds__(256, 4) void k_main(
    const float* __restrict__ uf, const float* __restrict__ vf,
    const unsigned short* __restrict__ w2t, const unsigned short* __restrict__ w3t,
    const float* __restrict__ b2, const float* __restrict__ b3,
    float* __restrict__ summed)
{
    __shared__ unsigned short tile[64 * 256];
    const int tid  = threadIdx.x;
    const int b    = blockIdx.y, tIdx = blockIdx.x;
    const int lane = tid & 63;
    const int wave = tid >> 6;
    const int n0   = wave * 64;            // wave's 64-column slice
    const int lm   = lane & 15, quad = lane >> 4;

    // ---- build h1 = relu(U_i + V_j) into LDS ----
    {
        const int r = tid >> 2, q4 = tid & 3;   // 4 threads per row
        const int p = tIdx * 64 + r;
        float sq = sqrtf(8.0f * (float)p + 1.0f);
        int i = (int)((sq - 1.0f) * 0.5f);
        while ((i + 1) * (i + 2) / 2 <= p) ++i;
        while (i * (i + 1) / 2 > p) --i;
        const int j = p - i * (i + 1) / 2;
        const float* up = uf + (b * 256 + i) * 256;
        const float* vp = vf + (b * 256 + j) * 256;
        const int fr = ((r & 7) << 2) | ((r >> 3) & 3);
        #pragma unroll
        for (int it = 0; it < 8; ++it) {
            const int c   = it * 4 + q4;        // logical chunk
            const int col = c << 3;
            float4 u0 = *(const float4*)(up + col);
            float4 u1 = *(const float4*)(up + col + 4);
            float4 v0 = *(const float4*)(vp + col);
            float4 v1 = *(const float4*)(vp + col + 4);
            uint4 w;
            w.x = pk2(fmaxf(u0.x + v0.x, 0.f), fmaxf(u0.y + v0.y, 0.f));
            w.y = pk2(fmaxf(u0.z + v0.z, 0.f), fmaxf(u0.w + v0.w, 0.f));
            w.z = pk2(fmaxf(u1.x + v1.x, 0.f), fmaxf(u1.y + v1.y, 0.f));
            w.w = pk2(fmaxf(u1.z + v1.z, 0.f), fmaxf(u1.w + v1.w, 0.f));
            *(uint4*)(&tile[r * 256 + ((c ^ fr) << 3)]) = w;
        }
    }
    __syncthreads();

    float b2c[4], b3c[4];
    #pragma unroll
    for (int nt = 0; nt < 4; ++nt) {
        b2c[nt] = b2[n0 + nt * 16 + lm];
        b3c[nt] = b3[n0 + nt * 16 + lm];
    }

    const float4v zero4 = {0.f, 0.f, 0.f, 0.f};
    float4v acc[4][4];
    #pragma unroll
    for (int mt = 0; mt < 4; ++mt)
        #pragma unroll
        for (int nt = 0; nt < 4; ++nt) acc[mt][nt] = zero4;

    // ---- GEMM1: h2 = h1 @ W2 ----
    const unsigned short* bb2 = w2t + (n0 + lm) * 256 + quad * 8;
    for (int ks = 0; ks < 8; ++ks) {
        short8 bfr[4];
        #pragma unroll
        for (int nt = 0; nt < 4; ++nt)
            bfr[nt] = *(const short8*)(bb2 + nt * 4096 + ks * 32);
        short8 afr[4];
        #pragma unroll
        for (int mt = 0; mt < 4; ++mt) {
            const int fr = ((lm & 7) << 2) | ((mt * 2 + (lm >> 3)) & 3);
            afr[mt] = *(const short8*)(&tile[(mt * 16 + lm) * 256 +
                                             (((ks * 4 + quad) ^ fr) << 3)]);
        }
        #pragma unroll
        for (int mt = 0; mt < 4; ++mt)
            #pragma unroll
            for (int nt = 0; nt < 4; ++nt)
                acc[mt][nt] = __builtin_amdgcn_mfma_f32_16x16x32_bf16(
                    afr[mt], bfr[nt], acc[mt][nt], 0, 0, 0);
    }
    __syncthreads();

    // ---- h2 = relu(acc + b2) back to LDS (pair-packed b32 writes) ----
    #pragma unroll
    for (int mt = 0; mt < 4; ++mt) {
        #pragma unroll
        for (int nt = 0; nt < 4; ++nt) {
            #pragma unroll
            for (int rg = 0; rg < 4; ++rg) {
                const int row = mt * 16 + quad * 4 + rg;
                float v   = fmaxf(acc[mt][nt][rg] + b2c[nt], 0.f);
                float vnb = __shfl_down(v, 1);
                if (!(lm & 1)) {
                    const int col = n0 + nt * 16 + lm;
                    const int fr  = ((row & 7) << 2) | ((row >> 3) & 3);
                    const int eo  = row * 256 + (((col >> 3) ^ fr) << 3) + (col & 7);
                    *(unsigned*)(&tile[eo]) = pk2(v, vnb);
                }
            }
        }
    }
    __syncthreads();

    // ---- GEMM2: rel = h2 @ W3 ----
    #pragma unroll
    for (int mt = 0; mt < 4; ++mt)
        #pragma unroll
        for (int nt = 0; nt < 4; ++nt) acc[mt][nt] = zero4;

    const unsigned short* bb3 = w3t + (n0 + lm) * 256 + quad * 8;
    for (int ks = 0; ks < 8; ++ks) {
        short8 bfr[4];
        #pragma unroll
        for (int nt = 0; nt < 4; ++nt)
            bfr[nt] = *(const short8*)(bb3 + nt * 4096 + ks * 32);
        short8 afr[4];
        #pragma unroll
        for (int mt = 0; mt < 4; ++mt) {
            const int fr = ((lm & 7) << 2) | ((mt * 2 + (lm >> 3)) & 3);
            afr[mt] = *(const short8*)(&tile[(mt * 16 + lm) * 256 +
                                             (((ks * 4 + quad) ^ fr) << 3)]);
        }
        #pragma unroll
        for (int mt = 0; mt < 4; ++mt)
            #pragma unroll
            for (int nt = 0; nt < 4; ++nt)
                acc[mt][nt] = __builtin_amdgcn_mfma_f32_16x16x32_bf16(
                    afr[mt], bfr[nt], acc[mt][nt], 0, 0, 0);
    }

    // ---- relu + row-sum over the 64 pairs of this tile -> atomic ----
    #pragma unroll
    for (int nt = 0; nt < 4; ++nt) {
        float s = 0.f;
        #pragma unroll
        for (int mt = 0; mt < 4; ++mt)
            #pragma unroll
            for (int rg = 0; rg < 4; ++rg)
                s += fmaxf(acc[mt][nt][rg] + b3c[nt], 0.f);
        s += __shfl_xor(s, 16);
        s += __shfl_xor(s, 32);
        if (quad == 0)
            atomicAdd(&summed[b * 256 + n0 + nt * 16 + lm], s);
    }
}

// ---- f_phi (fp32) --------------------------------------------------------
__global__ void k_tail(const float* __restrict__ summed,
                       const float* __restrict__ fw1, const float* __restrict__ fb1,
                       const float* __restrict__ fw2, const float* __restrict__ fb2,
                       const float* __restrict__ fw3, const float* __restrict__ fb3,
                       float* __restrict__ out) {
    __shared__ float s0[256], s1[256];
    const int b = blockIdx.x, d = threadIdx.x;
    s0[d] = summed[b * 256 + d];
    __syncthreads();
    float a1 = fb1[d];
    for (int k = 0; k < 256; ++k) a1 += s0[k] * fw1[k * 256 + d];
    s1[d] = fmaxf(a1, 0.f);
    __syncthreads();
    float a2 = fb2[d];
    for (int k = 0; k < 256; ++k) a2 += s1[k] * fw2[k * 256 + d];
    s0[d] = fmaxf(a2, 0.f);
    __syncthreads();
    if (d < 32) {
        float o = fb3[d];
        for (int k = 0; k < 256; ++k) o += s0[k] * fw3[k * 32 + d];
        out[b * 32 + d] = o;
    }
}

extern "C" void kernel_launch(void* const* d_in, const int* in_sizes, int n_in,
                              void* d_out, int out_size, void* d_ws, size_t ws_size,
                              hipStream_t stream) {
    const float* x    = (const float*)d_in[0];
    const float* code = (const float*)d_in[1];
    const float* gw1  = (const float*)d_in[2];
    const float* gb1  = (const float*)d_in[3];
    const float* gw2  = (const float*)d_in[4];
    const float* gb2  = (const float*)d_in[5];
    const float* gw3  = (const float*)d_in[6];
    const float* gb3  = (const float*)d_in[7];
    const float* fw1  = (const float*)d_in[8];
    const float* fb1  = (const float*)d_in[9];
    const float* fw2  = (const float*)d_in[10];
    const float* fb2  = (const float*)d_in[11];
    const float* fw3  = (const float*)d_in[12];
    const float* fb3  = (const float*)d_in[13];
    float* out = (float*)d_out;

    // workspace layout (bytes), total ~4.27 MB
    char* ws = (char*)d_ws;
    float*          uf     = (float*)(ws);                     // 2 MiB
    float*          vf     = (float*)(ws + 2097152);           // 2 MiB
    unsigned short* w2t    = (unsigned short*)(ws + 4194304);  // 128 KiB
    unsigned short* w3t    = (unsigned short*)(ws + 4325376);  // 128 KiB
    float*          qb     = (float*)(ws + 4456448);           // 8 KiB
    float*          summed = (float*)(ws + 4464640);           // 8 KiB

    hipMemsetAsync(summed, 0, 8 * 256 * sizeof(float), stream);
    hipLaunchKernelGGL(k_prep, dim3(40), dim3(256), 0, stream,
                       code, gw1, gb1, gw2, gw3, qb, w2t, w3t);
    hipLaunchKernelGGL(k_uv,  dim3(256, 8), dim3(256), 0, stream, x, gw1, qb, uf, vf);
    hipLaunchKernelGGL(k_main, dim3(NTILE, 8), dim3(256), 0, stream,
                       uf, vf, w2t, w3t, gb2, gb3, summed);
    hipLaunchKernelGGL(k_tail, dim3(8), dim3(256), 0, stream,
                       summed, fw1, fb1, fw2, fb2, fw3, fb3, out);
}